// Round 7
// baseline (695.723 us; speedup 1.0000x reference)
//
#include <hip/hip_runtime.h>

// RNN_64072322122514: B=4096, T=2048, F=8, H=32, O=8 Elman RNN, all fp32 I/O.
//   h_t = tanh(x_t @ W_ih^T + b_ih + b_hh + h_{t-1} @ W_hh^T);  y = h_T @ W_out^T + b_out
//
// R9 (resubmit — R6 bench was GPUAcquisitionTimeout, no data).
// R9: WAVE DE-PHASING + ISSUE DIET. R8b post-mortem: staging x via LDS
// removed only 34 of 186 idle clk -> x latency was NOT the stall either.
// Ledger (clk/SIMD-step, 2 waves): R6 516=330busy+186idle, R7 690=510+180,
// R8b 528=376+152. Hand-modeled chain is only ~225 clk and 2x issue=376,
// so ideal wall ~376 -> the 152 idle = the two waves per SIMD run in
// LOCKSTEP (identical streams, same launch, no barriers) and stall
// SIMULTANEOUSLY on the same lgkmcnt/trans windows. Fixes:
//   - skew: one-time s_sleep(4) (~256 clk ~ half-step) for waves picked by
//     (bx ^ bx>>8 ^ wave)&1 — anti-phases co-resident waves under either
//     plausible block->CU packing; offset persists (no in-loop barriers).
//   - diet: scalar x-projection fmas (no v2f broadcast movs). Bit-identical.
// Keep R8b x-LDS staging (it did remove ~34 clk and decouples global lat).
// Predict: 450 -> ~330-360 us, VALUBusy 71 -> 80-88%, absmax 0.00390625.
// Pre-commit: if dur >= 420 us & idle unchanged -> chain really ~500 clk ->
// R10 = swapped-MFMA rewrite (W_hh as A, 16 rows/wave).

typedef float v2f __attribute__((ext_vector_type(2)));
typedef _Float16 h2v __attribute__((ext_vector_type(2)));

static constexpr int T_STEPS = 2048;
static constexpr int FDIM    = 8;
static constexpr int HDIM    = 32;
static constexpr int ODIM    = 8;
static constexpr int ROWS_PER_BLOCK = 8;    // 4 waves x 2 rows
static constexpr int NWAVE   = 4;
static constexpr int CH      = 16;          // steps per chunk = 1 KB per wave
static constexpr int NCH     = T_STEPS / CH;   // 128 (even)
static constexpr int LSTR    = 40;          // fp16 LDS row stride for h

__device__ __forceinline__ float fdot2(h2v a, h2v b, float c) {
    return __builtin_amdgcn_fdot2(a, b, c, false);
}
__device__ __forceinline__ h2v bch(unsigned u) {
    return __builtin_bit_cast(h2v, u);
}

// Returns s + s_partner where partner = lane^16 (orientation-robust use of
// v_permlane16_swap_b32; proven bit-identical vs ds_swizzle xor16 in R7).
__device__ __forceinline__ float xor16_sum(float s) {
    float a = s, b;
    asm("v_mov_b32 %1, %0\n\t"
        "s_nop 1\n\t"
        "v_permlane16_swap_b32 %0, %1"
        : "+v"(a), "=&v"(b));
    return a + b;
}

// async global->LDS, 16 B per lane; lds dest = uniform base + lane*16.
__device__ __forceinline__ void gload_lds16(const void* g, void* l) {
    __builtin_amdgcn_global_load_lds(
        (const __attribute__((address_space(1))) void*)g,
        (__attribute__((address_space(3))) void*)l, 16, 0, 0);
}

__global__ __launch_bounds__(256, 2) void rnn_scan_kernel(
    const float* __restrict__ x,      // [B, T, F]
    const float* __restrict__ W_ih,   // [H, F]
    const float* __restrict__ W_hh,   // [H, H]
    const float* __restrict__ b_ih,   // [H]
    const float* __restrict__ b_hh,   // [H]
    const float* __restrict__ W_out,  // [O, H]
    const float* __restrict__ b_out,  // [O]
    float* __restrict__ out)          // [1, B, O]
{
    const float K = 2.8853900817779268f;  // 2*log2(e)
    const int tid  = threadIdx.x;
    const int lane = tid & 63;
    const int wave = tid >> 6;
    const int g    = lane & 15;           // dim-pair: dims {2g, 2g+1}
    const int c    = (lane >> 4) & 1;     // k-half [16c,16c+16), f-half [4c,4c+4)
    const int sub  = lane >> 5;           // which of the wave's 2 rows
    const int r    = wave * 2 + sub;      // row within block
    const int d0 = 2 * g, d1 = 2 * g + 1;

    __shared__ _Float16 hsh[ROWS_PER_BLOCK][LSTR];
    __shared__ alignas(16) float xA[NWAVE][CH * 16];   // [wave][16 steps x 2 rows x 32B]
    __shared__ alignas(16) float xB[NWAVE][CH * 16];

    // ---- resident weights (fp16, pre-scaled by K) ----
    h2v wA[8], wB[8];     // dims d0/d1 over k in [16c, 16c+16)
    const float* whr0 = W_hh + d0 * HDIM + 16 * c;
    const float* whr1 = W_hh + d1 * HDIM + 16 * c;
#pragma unroll
    for (int j = 0; j < 8; ++j) {
        h2v wa; wa[0] = (_Float16)(whr0[2 * j] * K); wa[1] = (_Float16)(whr0[2 * j + 1] * K);
        wA[j] = wa;
        h2v wb; wb[0] = (_Float16)(whr1[2 * j] * K); wb[1] = (_Float16)(whr1[2 * j + 1] * K);
        wB[j] = wb;
    }
    float wi0[4], wi1[4]; // xp weights (fp32) for f in [4c, 4c+4), dims d0/d1
#pragma unroll
    for (int f = 0; f < 4; ++f) {
        wi0[f] = W_ih[d0 * FDIM + 4 * c + f] * K;
        wi1[f] = W_ih[d1 * FDIM + 4 * c + f] * K;
    }
    const float bias0 = c ? 0.0f : (b_ih[d0] + b_hh[d0]) * K;
    const float bias1 = c ? 0.0f : (b_ih[d1] + b_hh[d1]) * K;

    hsh[r][2 * g + c] = (_Float16)0.0f;   // h_0 = 0 (covers all 32 dims)

    // h gather/publish pointers (R6 scheme)
    const uint4* hq = reinterpret_cast<const uint4*>(
        reinterpret_cast<const char*>(&hsh[r][0]) + 32 * c);
    _Float16* hw = &hsh[r][2 * g + c];

    // ---- x staging: lane i stages (row = i>>5, step = (i&31)>>1, half = i&1)
    // writer lane i lands at byte i*16 = sub*512 + step*32 + half*16  (matches reader)
    const int sj = lane & 31;
    const float* gsrc = x
        + ((size_t)blockIdx.x * ROWS_PER_BLOCK + wave * 2 + (lane >> 5)) * ((size_t)T_STEPS * FDIM)
        + (size_t)(sj >> 1) * FDIM + (size_t)(sj & 1) * 4;
    float* ldstA = &xA[wave][0];          // wave-uniform LDS base
    float* ldstB = &xB[wave][0];
    // reader base: this lane reads its row's f-half each step
    const char* rdA = reinterpret_cast<const char*>(&xA[wave][0]) + sub * 512 + c * 16;
    const char* rdB = reinterpret_cast<const char*>(&xB[wave][0]) + sub * 512 + c * 16;

    // ---- wave de-phasing: anti-phase co-resident waves so their stall
    // windows interleave (lockstep-TLP fix). One-time ~256 clk.
    if ((blockIdx.x ^ (blockIdx.x >> 8) ^ wave) & 1)
        __builtin_amdgcn_s_sleep(4);

#define ISSUE(dst, chunk) gload_lds16(gsrc + (size_t)(chunk) * (CH * FDIM), dst);

#define STEP(PBASE, S)                                                         \
    {                                                                          \
        float4 xr = *reinterpret_cast<const float4*>((PBASE) + (S) * 32);      \
        uint4 u0 = hq[0], u1 = hq[1];                                          \
        float c00 = 0.0f, c01 = 0.0f, c10 = 0.0f, c11 = 0.0f;                  \
        c00 = fdot2(wA[0], bch(u0.x), c00);  c10 = fdot2(wB[0], bch(u0.x), c10); \
        c01 = fdot2(wA[4], bch(u1.x), c01);  c11 = fdot2(wB[4], bch(u1.x), c11); \
        c00 = fdot2(wA[1], bch(u0.y), c00);  c10 = fdot2(wB[1], bch(u0.y), c10); \
        c01 = fdot2(wA[5], bch(u1.y), c01);  c11 = fdot2(wB[5], bch(u1.y), c11); \
        c00 = fdot2(wA[2], bch(u0.z), c00);  c10 = fdot2(wB[2], bch(u0.z), c10); \
        c01 = fdot2(wA[6], bch(u1.z), c01);  c11 = fdot2(wB[6], bch(u1.z), c11); \
        c00 = fdot2(wA[3], bch(u0.w), c00);  c10 = fdot2(wB[3], bch(u0.w), c10); \
        c01 = fdot2(wA[7], bch(u1.w), c01);  c11 = fdot2(wB[7], bch(u1.w), c11); \
        float a0 = bias0, a1 = bias1;                                          \
        a0 = fmaf(wi0[0], xr.x, a0);  a1 = fmaf(wi1[0], xr.x, a1);             \
        a0 = fmaf(wi0[1], xr.y, a0);  a1 = fmaf(wi1[1], xr.y, a1);             \
        a0 = fmaf(wi0[2], xr.z, a0);  a1 = fmaf(wi1[2], xr.z, a1);             \
        a0 = fmaf(wi0[3], xr.w, a0);  a1 = fmaf(wi1[3], xr.w, a1);             \
        float s0 = a0 + (c00 + c01);                                           \
        float s1 = a1 + (c10 + c11);                                           \
        float s0f = xor16_sum(s0);                                             \
        float s1f = xor16_sum(s1);                                             \
        float sv = c ? s1f : s0f;                                              \
        float ev = __builtin_amdgcn_exp2f(sv);                                 \
        float rc = __builtin_amdgcn_rcpf(ev + 1.0f);                           \
        *hw = (_Float16)fmaf(-2.0f, rc, 1.0f);                                 \
    }

#define CHUNK(PBASE)                                                           \
    {                                                                          \
        _Pragma("unroll")                                                      \
        for (int st = 0; st < CH; ++st) STEP(PBASE, st)                        \
    }

    // prologue: 2 chunks in flight
    ISSUE(ldstA, 0)
    ISSUE(ldstB, 1)

    for (int ci = 0; ci < NCH - 2; ci += 2) {
        asm volatile("s_waitcnt vmcnt(1)" ::: "memory");   // chunk ci (A) landed
        CHUNK(rdA)
        ISSUE(ldstA, ci + 2)                                // A free; refill
        asm volatile("s_waitcnt vmcnt(1)" ::: "memory");   // chunk ci+1 (B) landed
        CHUNK(rdB)
        ISSUE(ldstB, ci + 3)                                // B free; refill
    }
    // tail: chunks NCH-2 (A), NCH-1 (B); outstanding = {A, B}
    asm volatile("s_waitcnt vmcnt(1)" ::: "memory");
    CHUNK(rdA)
    asm volatile("s_waitcnt vmcnt(0)" ::: "memory");
    CHUNK(rdB)

#undef CHUNK
#undef STEP
#undef ISSUE

    // ---- epilogue: y = h_T @ W_out^T + b_out ----
    __syncthreads();
    if (tid < ROWS_PER_BLOCK * ODIM) {   // 64 threads
        const int rr = tid >> 3;
        const int o  = tid & 7;
        float acc = b_out[o];
#pragma unroll
        for (int j = 0; j < HDIM; ++j)
            acc = fmaf((float)hsh[rr][j], W_out[o * HDIM + j], acc);
        out[((long long)blockIdx.x * ROWS_PER_BLOCK + rr) * ODIM + o] = acc;
    }
}

extern "C" void kernel_launch(void* const* d_in, const int* in_sizes, int n_in,
                              void* d_out, int out_size, void* d_ws, size_t ws_size,
                              hipStream_t stream) {
    const float* x     = (const float*)d_in[0];
    const float* W_ih  = (const float*)d_in[1];
    const float* W_hh  = (const float*)d_in[2];
    const float* b_ih  = (const float*)d_in[3];
    const float* b_hh  = (const float*)d_in[4];
    const float* W_out = (const float*)d_in[5];
    const float* b_out = (const float*)d_in[6];

    const int B = in_sizes[0] / (T_STEPS * FDIM);   // 4096
    const int grid = B / ROWS_PER_BLOCK;            // 512 blocks = 2/CU

    rnn_scan_kernel<<<grid, 256, 0, stream>>>(
        x, W_ih, W_hh, b_ih, b_hh, W_out, b_out, (float*)d_out);
}